// Round 5
// baseline (306.694 us; speedup 1.0000x reference)
//
#include <hip/hip_runtime.h>
#include <stdint.h>

typedef __attribute__((ext_vector_type(8))) short short8;
typedef __attribute__((ext_vector_type(4))) float floatx4;

// ---------- helpers ----------
__device__ __forceinline__ float bf16_to_f(uint16_t u) {
    union { uint32_t i; float f; } v; v.i = ((uint32_t)u) << 16; return v.f;
}
__device__ __forceinline__ uint16_t f_to_bf16(float f) {
    union { uint32_t i; float f; } v; v.f = f;
    uint32_t u = v.i;
    u += 0x7FFFu + ((u >> 16) & 1u);   // round-to-nearest-even
    return (uint16_t)(u >> 16);
}
__device__ __forceinline__ void gload16(const void* g, void* l) {
    __builtin_amdgcn_global_load_lds(
        (const __attribute__((address_space(1))) void*)g,
        (__attribute__((address_space(3))) void*)l, 16, 0, 0);
}
__device__ __forceinline__ float rcpf(float x) { return __builtin_amdgcn_rcpf(x); }

#define B_  32
#define T_  512
#define CF_ 2048
#define H_  128
#define G4_ 512   // 4*H
#define LOG2E 1.4426950408889634f

// =====================================================================
// k_cvt_all: all 6 weight tensors fp32 -> bf16 in ONE launch.
// =====================================================================
__global__ __launch_bounds__(256) void k_cvt_all(
        const float* __restrict__ Wfc, const float* __restrict__ Wih_f,
        const float* __restrict__ Wih_b, const float* __restrict__ Whh_f,
        const float* __restrict__ Whh_b, const float* __restrict__ Wout,
        uint16_t* __restrict__ WfcB, uint16_t* __restrict__ WihB,
        uint16_t* __restrict__ WhhB, uint16_t* __restrict__ WoutB) {
    const int blk = blockIdx.x;
    const float* s; uint16_t* d; int off;
    if (blk < 256)      { s = Wfc;   d = WfcB;          off = blk; }
    else if (blk < 320) { s = Wih_f; d = WihB;          off = blk - 256; }
    else if (blk < 384) { s = Wih_b; d = WihB + 65536;  off = blk - 320; }
    else if (blk < 448) { s = Whh_f; d = WhhB;          off = blk - 384; }
    else if (blk < 512) { s = Whh_b; d = WhhB + 65536;  off = blk - 448; }
    else                { s = Wout;  d = WoutB;         off = blk - 512; }
    const int i = off * 1024 + threadIdx.x * 4;
    float4 v = *(const float4*)&s[i];
    ushort4 o;
    o.x = f_to_bf16(v.x); o.y = f_to_bf16(v.y);
    o.z = f_to_bf16(v.z); o.w = f_to_bf16(v.w);
    *(ushort4*)&d[i] = o;
}

// =====================================================================
// k_fc1x: fused x-transpose + fc1 + input-projection.
// Grid (T/32=16, B=32) = 512 WGs, 512 thr = 8 waves, 2 WG/CU.
// Phase A: Hfc_tile(128d x 32t) = W_fc1(128x2048) @ x[b](2048 x 32t)
//   Wave w owns d-rows [16w,16w+16). x fp32 -> LDS transpose tile
//   -> bf16 chunk-major Bs; W_fc1 via global_load_lds. Result -> Hs2.
// Phase B: Xp[dir][t][g] = Wih_dir @ Hfc_tile^T + b_dir.
//   Wave w: dir=w>>2, g-slab (w&3)*64 (+256 per it).
// =====================================================================
__global__ __launch_bounds__(512) void k_fc1x(const float* __restrict__ x,
                                              const uint16_t* __restrict__ WfcB,
                                              const float* __restrict__ bfc,
                                              const uint16_t* __restrict__ WihB,
                                              const float* __restrict__ b_f,
                                              const float* __restrict__ b_b,
                                              uint16_t* __restrict__ Xp) {
    __shared__ float tile[32 * 65];                    // [t][cf] fp32
    __shared__ __align__(16) uint16_t As[8192];        // W chunk-major (8c x 128r x 8)
    __shared__ __align__(16) uint16_t Bs[2176];        // xT chunk-major (8c x 34 x 8)
    __shared__ __align__(16) uint16_t Hs2[4352];       // Hfc chunk-major (16c x 34 x 8)

    const int bb = blockIdx.y, n0 = blockIdx.x * 32;
    const int tid = threadIdx.x, w = tid >> 6, l = tid & 63;
    const int lm = l & 15, lk = l >> 4;
    const float* xb = x + (size_t)bb * CF_ * T_;

    // stage-1 mapping (x load / tile write): one float4 per thread
    const int t4 = (tid & 7) * 4, cf_r = tid >> 3;     // cf_r in 0..63
    // stage-2 mapping (tile read / Bs write): one ushort4 per thread
    const int kk = (tid & 15) * 4, t_r = tid >> 4;     // t_r in 0..31

    float4 xv = *(const float4*)&xb[(size_t)cf_r * T_ + n0 + t4];

    // ---------------- Phase A ----------------
    const int dw = w * 16;                             // wave's d-slab
    floatx4 acc[2] = {};
    for (int k0 = 0; k0 < CF_; k0 += 64) {
        __syncthreads();
        // stage1: fp32 transpose tile
        tile[(t4 + 0) * 65 + cf_r] = xv.x;
        tile[(t4 + 1) * 65 + cf_r] = xv.y;
        tile[(t4 + 2) * 65 + cf_r] = xv.z;
        tile[(t4 + 3) * 65 + cf_r] = xv.w;
        // A staging: wave w stages chunk w (k-offset w*8), rows l and 64+l
        gload16(WfcB + (size_t)l * CF_ + k0 + w * 8,        As + (w * 128 + l) * 8);
        gload16(WfcB + (size_t)(64 + l) * CF_ + k0 + w * 8, As + (w * 128 + 64 + l) * 8);
        __syncthreads();
        // prefetch next x block
        if (k0 + 64 < CF_)
            xv = *(const float4*)&xb[(size_t)(k0 + 64 + cf_r) * T_ + n0 + t4];
        // stage2: tile -> bf16 chunk-major Bs
        {
            ushort4 o;
            o.x = f_to_bf16(tile[t_r * 65 + kk + 0]);
            o.y = f_to_bf16(tile[t_r * 65 + kk + 1]);
            o.z = f_to_bf16(tile[t_r * 65 + kk + 2]);
            o.w = f_to_bf16(tile[t_r * 65 + kk + 3]);
            *(ushort4*)&Bs[((kk >> 3) * 34 + t_r) * 8 + (kk & 7)] = o;
        }
        __syncthreads();
        // frags + MFMA
        short8 a[2], bfr[2][2];
        #pragma unroll
        for (int kf = 0; kf < 2; ++kf) {
            a[kf] = *(const short8*)&As[((kf * 4 + lk) * 128 + dw + lm) * 8];
            #pragma unroll
            for (int nf = 0; nf < 2; ++nf)
                bfr[nf][kf] = *(const short8*)&Bs[((kf * 4 + lk) * 34 + nf * 16 + lm) * 8];
        }
        #pragma unroll
        for (int nf = 0; nf < 2; ++nf) {
            acc[nf] = __builtin_amdgcn_mfma_f32_16x16x32_bf16(a[0], bfr[nf][0], acc[nf], 0, 0, 0);
            acc[nf] = __builtin_amdgcn_mfma_f32_16x16x32_bf16(a[1], bfr[nf][1], acc[nf], 0, 0, 0);
        }
    }
    __syncthreads();
    // epilogue A: bias + bf16 -> Hs2 chunk-major (16 chunks, stride 34)
    {
        const int d0 = dw + lk * 4;
        const float4 bv = *(const float4*)&bfc[d0];
        const int c = d0 >> 3;
        #pragma unroll
        for (int nf = 0; nf < 2; ++nf) {
            const int t = nf * 16 + lm;
            ushort4 o;
            o.x = f_to_bf16(acc[nf][0] + bv.x);
            o.y = f_to_bf16(acc[nf][1] + bv.y);
            o.z = f_to_bf16(acc[nf][2] + bv.z);
            o.w = f_to_bf16(acc[nf][3] + bv.w);
            *(ushort4*)&Hs2[(c * 34 + t) * 8 + (lk & 1) * 4] = o;
        }
    }
    __syncthreads();

    // ---------------- Phase B ----------------
    const int dirw = w >> 2;
    const int db   = dirw * B_ + bb;
    const uint16_t* Wp = WihB + (size_t)dirw * (G4_ * H_);
    const float* bi = dirw ? b_b : b_f;
    #pragma unroll
    for (int it = 0; it < 2; ++it) {
        const int gbase = (w & 3) * 64 + it * 256;
        short8 aw[4][4];
        #pragma unroll
        for (int mf = 0; mf < 4; ++mf)
            #pragma unroll
            for (int kf = 0; kf < 4; ++kf)
                aw[mf][kf] = *(const short8*)&Wp[(size_t)(gbase + mf * 16 + lm) * H_ + kf * 32 + lk * 8];
        short8 bbf[4];
        floatx4 acc2[4][2] = {};
        #pragma unroll
        for (int nf = 0; nf < 2; ++nf) {
            #pragma unroll
            for (int kf = 0; kf < 4; ++kf)
                bbf[kf] = *(const short8*)&Hs2[((kf * 4 + lk) * 34 + nf * 16 + lm) * 8];
            #pragma unroll
            for (int mf = 0; mf < 4; ++mf)
                #pragma unroll
                for (int kf = 0; kf < 4; ++kf)
                    acc2[mf][nf] = __builtin_amdgcn_mfma_f32_16x16x32_bf16(aw[mf][kf], bbf[kf], acc2[mf][nf], 0, 0, 0);
        }
        #pragma unroll
        for (int mf = 0; mf < 4; ++mf) {
            const int g0 = gbase + mf * 16 + lk * 4;
            const float4 bv = *(const float4*)&bi[g0];
            #pragma unroll
            for (int nf = 0; nf < 2; ++nf) {
                const int t = n0 + nf * 16 + lm;
                ushort4 o;
                o.x = f_to_bf16(acc2[mf][nf][0] + bv.x);
                o.y = f_to_bf16(acc2[mf][nf][1] + bv.y);
                o.z = f_to_bf16(acc2[mf][nf][2] + bv.z);
                o.w = f_to_bf16(acc2[mf][nf][3] + bv.w);
                *(ushort4*)&Xp[((size_t)db * T_ + t) * G4_ + g0] = o;
            }
        }
    }
}

// =====================================================================
// k_lstm: MFMA recurrence (unchanged).
// =====================================================================
__global__ __launch_bounds__(512) void k_lstm(const uint16_t* __restrict__ Xp,
                                              const uint16_t* __restrict__ WhhB,
                                              uint16_t* __restrict__ hs) {
    __shared__ __align__(16) uint16_t h_sh[16 * 136];
    __shared__ float z_sh[16 * 516];
    const int dir = blockIdx.y, t0 = blockIdx.x * 16;
    const int tid = threadIdx.x, w = tid >> 6, l = tid & 63;
    const int lm = l & 15, lk = l >> 4;
    const int gw = w * 64;
    const uint16_t* Wp = WhhB + dir * (G4_ * H_);

    short8 bw[4][4];
    #pragma unroll
    for (int nf = 0; nf < 4; ++nf)
        #pragma unroll
        for (int kf = 0; kf < 4; ++kf)
            bw[nf][kf] = *(const short8*)&Wp[(size_t)(gw + nf * 16 + lm) * H_ + kf * 32 + lk * 8];

    for (int i = tid; i < 16 * 136; i += 512) h_sh[i] = 0;
    const int hh = tid & 127, tq = tid >> 7;
    float c[4] = {0.f, 0.f, 0.f, 0.f};
    __syncthreads();

    for (int s = 0; s < 32; ++s) {
        const int b_idx = dir ? (31 - s) : s;
        const uint16_t* xp = Xp + ((size_t)(dir * B_ + b_idx) * T_ + t0) * G4_;
        uint16_t xv[4][4];
        #pragma unroll
        for (int j = 0; j < 4; ++j)
            #pragma unroll
            for (int gg = 0; gg < 4; ++gg)
                xv[j][gg] = xp[(size_t)(tq * 4 + j) * G4_ + gg * H_ + hh];

        short8 af[4];
        #pragma unroll
        for (int kf = 0; kf < 4; ++kf)
            af[kf] = *(const short8*)&h_sh[lm * 136 + kf * 32 + lk * 8];
        floatx4 acc[4] = {};
        #pragma unroll
        for (int nf = 0; nf < 4; ++nf)
            #pragma unroll
            for (int kf = 0; kf < 4; ++kf)
                acc[nf] = __builtin_amdgcn_mfma_f32_16x16x32_bf16(af[kf], bw[nf][kf], acc[nf], 0, 0, 0);
        #pragma unroll
        for (int nf = 0; nf < 4; ++nf)
            #pragma unroll
            for (int r = 0; r < 4; ++r)
                z_sh[(lk * 4 + r) * 516 + gw + nf * 16 + lm] = acc[nf][r];
        __syncthreads();

        #pragma unroll
        for (int j = 0; j < 4; ++j) {
            const int t = tq * 4 + j;
            const float* zr = &z_sh[t * 516];
            float zi = zr[hh]            + bf16_to_f(xv[j][0]);
            float zf = zr[H_ + hh]       + bf16_to_f(xv[j][1]);
            float zg = zr[2 * H_ + hh]   + bf16_to_f(xv[j][2]);
            float zo = zr[3 * H_ + hh]   + bf16_to_f(xv[j][3]);
            float si = rcpf(1.f + __builtin_amdgcn_exp2f(-LOG2E * zi));
            float sf = rcpf(1.f + __builtin_amdgcn_exp2f(-LOG2E * zf));
            float so = rcpf(1.f + __builtin_amdgcn_exp2f(-LOG2E * zo));
            float tg = 1.f - 2.f * rcpf(1.f + __builtin_amdgcn_exp2f(2.f * LOG2E * zg));
            c[j] = sf * c[j] + si * tg;
            float tc = 1.f - 2.f * rcpf(1.f + __builtin_amdgcn_exp2f(2.f * LOG2E * c[j]));
            float hn = so * tc;
            uint16_t hb = f_to_bf16(hn);
            h_sh[t * 136 + hh] = hb;
            hs[((size_t)b_idx * T_ + t0 + t) * 256 + dir * H_ + hh] = hb;
        }
        __syncthreads();
    }
}

// =====================================================================
// k_outm: out[b][e][t] fp32 = W_out(128x256) @ hs[b]^T + b_out
// 64x64 tiles, BK=64, grid (8, 2, 32)
// =====================================================================
__global__ __launch_bounds__(256) void k_outm(const uint16_t* __restrict__ WoutB,
                                              const uint16_t* __restrict__ hs,
                                              const float* __restrict__ bout,
                                              float* __restrict__ out) {
    __shared__ __align__(16) uint16_t As[4096], Bs[4096];
    const int b = blockIdx.z, m0 = blockIdx.y * 64, n0 = blockIdx.x * 64;
    const int tid = threadIdx.x, w = tid >> 6, l = tid & 63;
    const int wm = (w >> 1) * 32, wn = (w & 1) * 32;
    const int lm = l & 15, lk = l >> 4;
    const uint16_t* gA = WoutB + (size_t)(m0 + l) * 256;
    const uint16_t* gB = hs + ((size_t)b * T_ + n0 + l) * 256;
    floatx4 acc[2][2] = {};
    for (int k0 = 0; k0 < 256; k0 += 64) {
        __syncthreads();
        gload16(gA + k0 + (2 * w) * 8,     As + ((2 * w) * 64 + l) * 8);
        gload16(gA + k0 + (2 * w + 1) * 8, As + ((2 * w + 1) * 64 + l) * 8);
        gload16(gB + k0 + (2 * w) * 8,     Bs + ((2 * w) * 64 + l) * 8);
        gload16(gB + k0 + (2 * w + 1) * 8, Bs + ((2 * w + 1) * 64 + l) * 8);
        __syncthreads();
        short8 a[2][2], bfr[2][2];
        #pragma unroll
        for (int kf = 0; kf < 2; ++kf) {
            #pragma unroll
            for (int mf = 0; mf < 2; ++mf)
                a[mf][kf] = *(const short8*)&As[((kf * 4 + lk) * 64 + wm + mf * 16 + lm) * 8];
            #pragma unroll
            for (int nf = 0; nf < 2; ++nf)
                bfr[nf][kf] = *(const short8*)&Bs[((kf * 4 + lk) * 64 + wn + nf * 16 + lm) * 8];
        }
        #pragma unroll
        for (int mf = 0; mf < 2; ++mf)
            #pragma unroll
            for (int nf = 0; nf < 2; ++nf) {
                acc[mf][nf] = __builtin_amdgcn_mfma_f32_16x16x32_bf16(a[mf][0], bfr[nf][0], acc[mf][nf], 0, 0, 0);
                acc[mf][nf] = __builtin_amdgcn_mfma_f32_16x16x32_bf16(a[mf][1], bfr[nf][1], acc[mf][nf], 0, 0, 0);
            }
    }
    #pragma unroll
    for (int mf = 0; mf < 2; ++mf) {
        const int e0 = m0 + wm + mf * 16 + lk * 4;
        const float4 bv = *(const float4*)&bout[e0];
        #pragma unroll
        for (int nf = 0; nf < 2; ++nf) {
            const int t = n0 + wn + nf * 16 + lm;
            out[((size_t)b * H_ + e0 + 0) * T_ + t] = acc[mf][nf][0] + bv.x;
            out[((size_t)b * H_ + e0 + 1) * T_ + t] = acc[mf][nf][1] + bv.y;
            out[((size_t)b * H_ + e0 + 2) * T_ + t] = acc[mf][nf][2] + bv.z;
            out[((size_t)b * H_ + e0 + 3) * T_ + t] = acc[mf][nf][3] + bv.w;
        }
    }
}

// =====================================================================
extern "C" void kernel_launch(void* const* d_in, const int* in_sizes, int n_in,
                              void* d_out, int out_size, void* d_ws, size_t ws_size,
                              hipStream_t stream) {
    const float* x     = (const float*)d_in[0];
    const float* Wfc   = (const float*)d_in[1];
    const float* bfc   = (const float*)d_in[2];
    const float* Wih_f = (const float*)d_in[3];
    const float* Whh_f = (const float*)d_in[4];
    const float* b_f   = (const float*)d_in[5];
    const float* Wih_b = (const float*)d_in[6];
    const float* Whh_b = (const float*)d_in[7];
    const float* b_b   = (const float*)d_in[8];
    const float* Wout  = (const float*)d_in[9];
    const float* bout  = (const float*)d_in[10];
    float* out = (float*)d_out;

    char* ws = (char*)d_ws;
    uint16_t* Xp    = (uint16_t*)(ws);                 // 33,554,432 B
    uint16_t* hsB   = (uint16_t*)(ws + 33554432);      //  8,388,608 B
    uint16_t* WfcB  = (uint16_t*)(ws + 41943040);      //    524,288 B
    uint16_t* WihB  = (uint16_t*)(ws + 42467328);      //    262,144 B
    uint16_t* WhhB  = (uint16_t*)(ws + 42729472);      //    262,144 B
    uint16_t* WoutB = (uint16_t*)(ws + 42991616);      //     65,536 B

    k_cvt_all<<<dim3(544), 256, 0, stream>>>(Wfc, Wih_f, Wih_b, Whh_f, Whh_b, Wout,
                                             WfcB, WihB, WhhB, WoutB);
    k_fc1x <<<dim3(16, 32),  512, 0, stream>>>(x, WfcB, bfc, WihB, b_f, b_b, Xp);
    k_lstm <<<dim3(32, 2),   512, 0, stream>>>(Xp, WhhB, hsB);
    k_outm <<<dim3(8, 2, 32), 256, 0, stream>>>(WoutB, hsB, bout, out);
}